// Round 2
// baseline (1001.427 us; speedup 1.0000x reference)
//
#include <hip/hip_runtime.h>
#include <math.h>

#define B_LEN 1024
#define T_LEN 256
#define HST 36   // hid_sh leading stride keeps float4 access conflict-light
#define TS 20    // dxT/ypT row stride (17 used + 3 pad): banks 20*r%32 distinct

__device__ __forceinline__ float fast_rcp(float x) { return __builtin_amdgcn_rcpf(x); }
__device__ __forceinline__ float fast_rsq(float x) { return __builtin_amdgcn_rsqf(x); }
__device__ __forceinline__ float lane_bcast(float v, int l) {
    return __int_as_float(__builtin_amdgcn_readlane(__float_as_int(v), l));
}
__device__ __forceinline__ float fast_tanh(float x) {
    float e = __expf(2.0f * x);
    return 1.0f - 2.0f * fast_rcp(e + 1.0f);
}
__device__ __forceinline__ float softplus_f(float x) {
    return (x > 20.0f) ? x : log1pf(expf(x));
}
// weighted 17-dot: 0.0625*sum(all 17) + (2-0.0625)*center  (Wc0=2, rest 1/16)
__device__ __forceinline__ float wdot17(const float* __restrict__ a,
                                        const float* __restrict__ b) {
    float full = 0.0f;
    #pragma unroll
    for (int c = 0; c < 4; ++c) {
        const float4 av = *(const float4*)&a[c * 4];
        const float4 bv = *(const float4*)&b[c * 4];
        full += av.x * bv.x + av.y * bv.y + av.z * bv.z + av.w * bv.w;
    }
    full += a[16] * b[16];
    return 0.0625f * full + 1.9375f * a[0] * b[0];
}

// SINGLE WAVE PER BATCH (64-thread blocks, grid=1024, 4 blocks/CU).
// Zero __syncthreads: every producer->consumer hop is same-wave in-order LDS
// (pattern already proven in the 2-wave version for Sy_sh/K_sh/Pp_sh).
// chol8 + deferred qe-LDL fused branchless in one j-loop (2 serial chains
// interleaved). Pxy+Sy merged into one masked wdot17 round. Si in registers.
// qe(t) computed at top of step t+1 from retained Ppc regs; t=1 runs LDL on
// identity -> writes required q[:,0]=0; final qe emitted after the loop.
__global__ __launch_bounds__(64, 1)
void ukf_kernel(const float* __restrict__ X0, const float* __restrict__ U,
                const float* __restrict__ Y,  const float* __restrict__ W1,
                const float* __restrict__ B1, const float* __restrict__ W2,
                const float* __restrict__ B2, const float* __restrict__ HM,
                const float* __restrict__ LQ, const float* __restrict__ LR,
                const float* __restrict__ LP0, float* __restrict__ out)
{
    const int lane = threadIdx.x;     // 0..63, one wave
    const int b    = blockIdx.x;
    const int k8   = lane & 7;        // column / j8
    const int g8   = lane >> 3;       // row group / i8
    const int i8   = g8;
    const int j8   = k8;
    const int h32  = lane & 31;
    const int p2   = lane >> 5;       // half-wave (L1 row parity)
    const int m4   = lane & 3;
    const int sy   = lane >> 2;       // 0..15

    __shared__ __align__(16) float u_sh[T_LEN * 2];
    __shared__ __align__(16) float y_sh[T_LEN * 4];
    __shared__ __align__(16) float pts_sh[17 * 8];
    __shared__ __align__(16) float hid_sh[17 * HST];
    __shared__ __align__(16) float pf_sh[17 * 8];
    __shared__ __align__(16) float dxT_sh[8 * TS];   // dxT[d][s]
    __shared__ __align__(16) float ypT_sh[4 * TS];   // ypT[m][s]
    __shared__ __align__(16) float xp_sh[8];
    __shared__ __align__(16) float ypred_sh[4];
    __shared__ __align__(16) float Sy_sh[16];
    __shared__ __align__(16) float Pxy_sh[32];
    __shared__ __align__(16) float K_sh[32];
    __shared__ __align__(16) float Pp_sh[64];

    // ---- one-time staging (vectorized) ----
    {
        const float4* Uv = (const float4*)(U + (size_t)b * (T_LEN * 2));
        float4* us = (float4*)u_sh;
        #pragma unroll
        for (int k = 0; k < 2; ++k) us[k * 64 + lane] = Uv[k * 64 + lane];
        const float4* Yv = (const float4*)(Y + (size_t)b * (T_LEN * 4));
        float4* ys = (float4*)y_sh;
        #pragma unroll
        for (int k = 0; k < 4; ++k) ys[k * 64 + lane] = Yv[k * 64 + lane];
    }

    float w1r[10];
    #pragma unroll
    for (int d = 0; d < 10; ++d) w1r[d] = W1[d * 32 + h32];
    const float b1r = B1[h32];
    float w2r[32];
    #pragma unroll
    for (int h = 0; h < 32; ++h) w2r[h] = W2[h * 8 + k8];
    const float b2r = B2[k8];
    float hmr[8];
    #pragma unroll
    for (int d = 0; d < 8; ++d) hmr[d] = HM[m4 * 8 + d];

    const float qdiag = softplus_f(LQ[g8]);
    const float rdiag = softplus_f(LR[m4]);

    const size_t Xbase = (size_t)b * T_LEN * 8;
    const size_t Pbase = (size_t)B_LEN * T_LEN * 8  + (size_t)b * T_LEN * 64;
    const size_t qbase = (size_t)B_LEN * T_LEN * 72 + (size_t)b * T_LEN;
    const size_t rbase = (size_t)B_LEN * T_LEN * 73 + (size_t)b * T_LEN;

    // ---- persistent register state: x replicated, P column k8, Ppred col k8 ----
    float xn[8], Pc[8], Ppc[8];
    {
        const float4 xa = *(const float4*)&X0[b * 8];
        const float4 xb = *(const float4*)&X0[b * 8 + 4];
        xn[0] = xa.x; xn[1] = xa.y; xn[2] = xa.z; xn[3] = xa.w;
        xn[4] = xb.x; xn[5] = xb.y; xn[6] = xb.z; xn[7] = xb.w;
        const float p0k = softplus_f(LP0[k8]);
        #pragma unroll
        for (int i = 0; i < 8; ++i) {
            Pc[i]  = (i == k8) ? p0k : 0.0f;
            Ppc[i] = (i == k8) ? 1.0f : 0.0f;   // identity -> deferred qe(0)=0
        }
    }
    out[Pbase + lane] = Pc[g8];                  // coalesced 64-lane P store
    if (lane == 0) {
        *(float4*)&out[Xbase]     = make_float4(xn[0], xn[1], xn[2], xn[3]);
        *(float4*)&out[Xbase + 4] = make_float4(xn[4], xn[5], xn[6], xn[7]);
        out[rbase] = 0.0f;
    }

    for (int t = 1; t < T_LEN; ++t) {
        // ===== S1: fused branchless column-chol8(8P+jit) + prev-step qe-LDL ==
        float a[8];
        #pragma unroll
        for (int i = 0; i < 8; ++i) a[i] = 8.0f * Pc[i] + ((i == k8) ? 1e-4f : 0.0f);
        float qe = 0.0f;
        #pragma unroll
        for (int j = 0; j < 8; ++j) {
            const float dj = lane_bcast(a[j], j);
            const float dq = lane_bcast(Ppc[j], j);
            const float rv = fast_rsq(dj);
            const float rq = fast_rcp(dq);
            qe += __logf(dq);
            const float sc = (k8 == j) ? rv : 1.0f;
            const float tc = (k8 > j) ? a[j] * (rv * rv) : 0.0f;
            const float tq = (k8 > j) ? Ppc[j] * rq : 0.0f;
            float uc[8], uq[8];
            #pragma unroll
            for (int i = j + 1; i < 8; ++i) {
                uc[i] = lane_bcast(a[i], j);
                uq[i] = lane_bcast(Ppc[i], j);
            }
            #pragma unroll
            for (int i = j + 1; i < 8; ++i) {
                a[i]   = sc * a[i] - tc * uc[i];       // k8==j: *rv; k8>j: rank-1
                Ppc[i] = fmaf(-tq, uq[i], Ppc[i]);     // Gaussian elim (LDL diag)
            }
            a[j] = (k8 == j) ? dj * rv : a[j];
        }
        if (lane == 0) out[qbase + (t - 1)] = 0.5f * qe;

        // sigma points -> LDS (rows: 0 center, 1..8 +L, 9..16 -L)
        {
            float Lc[8];
            #pragma unroll
            for (int i = 0; i < 8; ++i) Lc[i] = (i >= k8) ? a[i] : 0.0f;
            if (g8 == 0) {
                *(float4*)&pts_sh[(1 + k8) * 8] =
                    make_float4(xn[0] + Lc[0], xn[1] + Lc[1], xn[2] + Lc[2], xn[3] + Lc[3]);
                *(float4*)&pts_sh[(1 + k8) * 8 + 4] =
                    make_float4(xn[4] + Lc[4], xn[5] + Lc[5], xn[6] + Lc[6], xn[7] + Lc[7]);
            } else if (g8 == 1) {
                *(float4*)&pts_sh[(9 + k8) * 8] =
                    make_float4(xn[0] - Lc[0], xn[1] - Lc[1], xn[2] - Lc[2], xn[3] - Lc[3]);
                *(float4*)&pts_sh[(9 + k8) * 8 + 4] =
                    make_float4(xn[4] - Lc[4], xn[5] - Lc[5], xn[6] - Lc[6], xn[7] - Lc[7]);
            } else if (g8 == 2 && k8 == 0) {
                *(float4*)&pts_sh[0] = make_float4(xn[0], xn[1], xn[2], xn[3]);
                *(float4*)&pts_sh[4] = make_float4(xn[4], xn[5], xn[6], xn[7]);
            }
        }

        // ===== S2: NN layer 1 (17 rows x 32 hidden; 2 rows/iter via p2) ======
        {
            const float u0 = u_sh[(t - 1) * 2 + 0];
            const float u1 = u_sh[(t - 1) * 2 + 1];
            const float ub = b1r + u0 * w1r[8] + u1 * w1r[9];
            #pragma unroll
            for (int p = 0; p < 8; ++p) {
                const int s = 2 * p + p2;                 // rows 0..15
                const float4 pa = *(const float4*)&pts_sh[s * 8];
                const float4 pb = *(const float4*)&pts_sh[s * 8 + 4];
                float acc = ub
                    + pa.x * w1r[0] + pa.y * w1r[1] + pa.z * w1r[2] + pa.w * w1r[3]
                    + pb.x * w1r[4] + pb.y * w1r[5] + pb.z * w1r[6] + pb.w * w1r[7];
                hid_sh[s * HST + h32] = fast_tanh(acc);
            }
            if (p2 == 0) {                                // row 16
                const float4 pa = *(const float4*)&pts_sh[16 * 8];
                const float4 pb = *(const float4*)&pts_sh[16 * 8 + 4];
                float acc = ub
                    + pa.x * w1r[0] + pa.y * w1r[1] + pa.z * w1r[2] + pa.w * w1r[3]
                    + pb.x * w1r[4] + pb.y * w1r[5] + pb.z * w1r[6] + pb.w * w1r[7];
                hid_sh[16 * HST + h32] = fast_tanh(acc);
            }
        }
        // layer 2: rows 0-7, 8-15 (64 lanes = 8 rows x 8 outs), then row 16
        #pragma unroll
        for (int rr = 0; rr < 2; ++rr) {
            const int srow = rr * 8 + g8;
            float acc = b2r;
            #pragma unroll
            for (int h = 0; h < 32; h += 4) {
                const float4 hv = *(const float4*)&hid_sh[srow * HST + h];
                acc += hv.x * w2r[h] + hv.y * w2r[h + 1] + hv.z * w2r[h + 2] + hv.w * w2r[h + 3];
            }
            pf_sh[srow * 8 + k8] = pts_sh[srow * 8 + k8] + acc;
        }
        if (lane < 8) {
            float a16 = b2r;
            #pragma unroll
            for (int h = 0; h < 32; h += 4) {
                const float4 hv = *(const float4*)&hid_sh[16 * HST + h];
                a16 += hv.x * w2r[h] + hv.y * w2r[h + 1] + hv.z * w2r[h + 2] + hv.w * w2r[h + 3];
            }
            pf_sh[16 * 8 + lane] = pts_sh[16 * 8 + lane] + a16;
        }

        // ===== S3: x_pred + dxT, then y_pts + ypred + ypT (same wave) ========
        {
            const float v0   = pf_sh[i8 * 8 + j8];
            const float v1   = pf_sh[(8 + i8) * 8 + j8];
            const float pf16 = (i8 == 0) ? pf_sh[16 * 8 + j8] : 0.0f;
            float part = ((i8 == 0) ? pf16 : v0) + v1;    // s=16 replaces s=0
            part += __shfl_xor(part, 8);
            part += __shfl_xor(part, 16);
            part += __shfl_xor(part, 32);
            const float xp = part * 0.0625f;
            if (i8 == 0) xp_sh[j8] = xp;
            dxT_sh[j8 * TS + i8]     = v0 - xp;           // dxT[d][s]
            dxT_sh[j8 * TS + 8 + i8] = v1 - xp;
            if (i8 == 0) dxT_sh[j8 * TS + 16] = pf16 - xp;
        }
        {
            float yv0, yv16 = 0.0f;
            {
                const float4 pa = *(const float4*)&pf_sh[sy * 8];
                const float4 pb = *(const float4*)&pf_sh[sy * 8 + 4];
                yv0 = pa.x * hmr[0] + pa.y * hmr[1] + pa.z * hmr[2] + pa.w * hmr[3]
                    + pb.x * hmr[4] + pb.y * hmr[5] + pb.z * hmr[6] + pb.w * hmr[7];
            }
            if (sy == 0) {
                const float4 pa = *(const float4*)&pf_sh[16 * 8];
                const float4 pb = *(const float4*)&pf_sh[16 * 8 + 4];
                yv16 = pa.x * hmr[0] + pa.y * hmr[1] + pa.z * hmr[2] + pa.w * hmr[3]
                     + pb.x * hmr[4] + pb.y * hmr[5] + pb.z * hmr[6] + pb.w * hmr[7];
            }
            float py = (sy == 0) ? yv16 : yv0;
            py += __shfl_xor(py, 4);
            py += __shfl_xor(py, 8);
            py += __shfl_xor(py, 16);
            py += __shfl_xor(py, 32);
            const float ypred = py * 0.0625f;
            if (lane < 4) ypred_sh[lane] = ypred;
            ypT_sh[m4 * TS + sy] = yv0 - ypred;           // ypT[m][s]
            if (sy == 0) ypT_sh[m4 * TS + 16] = yv16 - ypred;
        }

        // ===== S4: covariances. Round1: Ppred (64 lanes). ====================
        // Round2 merged: lanes<32 -> Pxy(ii,mm); lanes 32..47 -> Sy(s2,m4).
        {
            const float pv = wdot17(&dxT_sh[i8 * TS], &dxT_sh[j8 * TS])
                           + ((i8 == j8) ? (qdiag + 1e-4f) : 0.0f);
            Pp_sh[lane] = pv;

            const int r2 = (lane < 32) ? sy : (sy & 3);
            const float* pa2 = (lane < 32) ? &dxT_sh[r2 * TS] : &ypT_sh[r2 * TS];
            float v2 = wdot17(pa2, &ypT_sh[m4 * TS]);
            v2 += ((lane >= 32) && (r2 == m4)) ? rdiag : 0.0f;
            if (lane < 32)      Pxy_sh[lane] = v2;
            else if (lane < 48) Sy_sh[r2 * 4 + m4] = v2;

            #pragma unroll
            for (int i = 0; i < 8; ++i) Ppc[i] = Pp_sh[i * 8 + k8];  // in-order
        }

        // ===== S5: replicated chol4(Sy) -> Sy^-1 in registers + r_e ==========
        float Si[16];
        {
            const float4 r0v = *(const float4*)&Sy_sh[0];
            const float4 r1v = *(const float4*)&Sy_sh[4];
            const float4 r2v = *(const float4*)&Sy_sh[8];
            const float4 r3v = *(const float4*)&Sy_sh[12];
            const float d0 = r0v.x;
            const float r0 = fast_rsq(d0);
            const float L10 = r1v.x * r0, L20 = r2v.x * r0, L30 = r3v.x * r0;
            const float d1 = r1v.y - L10 * L10;
            const float r1 = fast_rsq(d1);
            const float L21 = (r2v.y - L20 * L10) * r1;
            const float L31 = (r3v.y - L30 * L10) * r1;
            const float d2_ = r2v.z - L20 * L20 - L21 * L21;
            const float rr2 = fast_rsq(d2_);
            const float L32 = (r3v.z - L30 * L20 - L31 * L21) * rr2;
            const float d3 = r3v.w - L30 * L30 - L31 * L31 - L32 * L32;
            const float r3 = fast_rsq(d3);
            if (lane == 0)
                out[rbase + t] = 0.5f * (__logf(d0) + __logf(d1) + __logf(d2_) + __logf(d3));
            float z1 = -L10 * r0 * r1;
            float z2 = -(L20 * r0 + L21 * z1) * rr2;
            float z3 = -(L30 * r0 + L31 * z1 + L32 * z2) * r3;
            float c03 = z3 * r3;
            float c02 = (z2 - L32 * c03) * rr2;
            float c01 = (z1 - L21 * c02 - L31 * c03) * r1;
            float c00 = (r0 - L10 * c01 - L20 * c02 - L30 * c03) * r0;
            float z2b = -L21 * r1 * rr2;
            float z3b = -(L31 * r1 + L32 * z2b) * r3;
            float c13 = z3b * r3;
            float c12 = (z2b - L32 * c13) * rr2;
            float c11 = (r1 - L21 * c12 - L31 * c13) * r1;
            float c10 = (-L10 * c11 - L20 * c12 - L30 * c13) * r0;
            float z3c = -L32 * rr2 * r3;
            float c23 = z3c * r3;
            float c22 = (rr2 - L32 * c23) * rr2;
            float c21 = (-L21 * c22 - L31 * c23) * r1;
            float c20 = (-L10 * c21 - L20 * c22 - L30 * c23) * r0;
            float c33 = r3 * r3;
            float c32 = (-L32 * c33) * rr2;
            float c31 = (-L21 * c32 - L31 * c33) * r1;
            float c30 = (-L10 * c31 - L20 * c32 - L30 * c33) * r0;
            const float s01 = 0.5f * (c01 + c10), s02 = 0.5f * (c02 + c20);
            const float s03 = 0.5f * (c03 + c30), s12 = 0.5f * (c12 + c21);
            const float s13 = 0.5f * (c13 + c31), s23 = 0.5f * (c23 + c32);
            Si[0]  = c00; Si[1]  = s01; Si[2]  = s02; Si[3]  = s03;
            Si[4]  = s01; Si[5]  = c11; Si[6]  = s12; Si[7]  = s13;
            Si[8]  = s02; Si[9]  = s12; Si[10] = c22; Si[11] = s23;
            Si[12] = s03; Si[13] = s13; Si[14] = s23; Si[15] = c33;
        }

        // ===== S6: K = Pxy*Si, P_new, x_new, stores ==========================
        {
            const float4 pr = *(const float4*)&Pxy_sh[k8 * 4];     // Pxy row k8
            float kk[4];
            #pragma unroll
            for (int aa = 0; aa < 4; ++aa)
                kk[aa] = pr.x * Si[0 * 4 + aa] + pr.y * Si[1 * 4 + aa]
                       + pr.z * Si[2 * 4 + aa] + pr.w * Si[3 * 4 + aa];
            if (g8 == 0) *(float4*)&K_sh[k8 * 4] = make_float4(kk[0], kk[1], kk[2], kk[3]);
            float K_[32];
            #pragma unroll
            for (int r = 0; r < 8; ++r) {
                const float4 kr = *(const float4*)&K_sh[r * 4];    // in-order
                K_[r * 4 + 0] = kr.x; K_[r * 4 + 1] = kr.y;
                K_[r * 4 + 2] = kr.z; K_[r * 4 + 3] = kr.w;
            }
            // P_new column k8 = Ppc - K * Pxy[k8,:]^T  (+ jitter). Ppc regs
            // survive into next iteration's deferred qe-LDL.
            #pragma unroll
            for (int i = 0; i < 8; ++i) {
                const float m = K_[i * 4 + 0] * pr.x + K_[i * 4 + 1] * pr.y
                              + K_[i * 4 + 2] * pr.z + K_[i * 4 + 3] * pr.w;
                Pc[i] = Ppc[i] - m + ((i == k8) ? 1e-4f : 0.0f);
            }
            const float4 yt = *(const float4*)&y_sh[t * 4];
            const float4 yp = *(const float4*)&ypred_sh[0];
            const float in0 = yt.x - yp.x, in1 = yt.y - yp.y;
            const float in2 = yt.z - yp.z, in3 = yt.w - yp.w;
            const float4 xpa = *(const float4*)&xp_sh[0];
            const float4 xpb = *(const float4*)&xp_sh[4];
            const float xpv[8] = {xpa.x, xpa.y, xpa.z, xpa.w, xpb.x, xpb.y, xpb.z, xpb.w};
            #pragma unroll
            for (int i = 0; i < 8; ++i)
                xn[i] = xpv[i] + K_[i * 4 + 0] * in0 + K_[i * 4 + 1] * in1
                               + K_[i * 4 + 2] * in2 + K_[i * 4 + 3] * in3;
            out[Pbase + (size_t)t * 64 + lane] = Pc[g8];
            if (lane == 0) {
                *(float4*)&out[Xbase + (size_t)t * 8]     = make_float4(xn[0], xn[1], xn[2], xn[3]);
                *(float4*)&out[Xbase + (size_t)t * 8 + 4] = make_float4(xn[4], xn[5], xn[6], xn[7]);
            }
        }
    }

    // final deferred qe for t = T_LEN-1
    {
        float qe = 0.0f;
        #pragma unroll
        for (int j = 0; j < 8; ++j) {
            const float dq = lane_bcast(Ppc[j], j);
            const float rq = fast_rcp(dq);
            qe += __logf(dq);
            const float tq = (k8 > j) ? Ppc[j] * rq : 0.0f;
            float uq[8];
            #pragma unroll
            for (int i = j + 1; i < 8; ++i) uq[i] = lane_bcast(Ppc[i], j);
            #pragma unroll
            for (int i = j + 1; i < 8; ++i) Ppc[i] = fmaf(-tq, uq[i], Ppc[i]);
        }
        if (lane == 0) out[qbase + (T_LEN - 1)] = 0.5f * qe;
    }
}

extern "C" void kernel_launch(void* const* d_in, const int* in_sizes, int n_in,
                              void* d_out, int out_size, void* d_ws, size_t ws_size,
                              hipStream_t stream) {
    (void)in_sizes; (void)n_in; (void)out_size; (void)d_ws; (void)ws_size;
    const float* X0 = (const float*)d_in[0];
    const float* U  = (const float*)d_in[1];
    const float* Y  = (const float*)d_in[2];
    const float* W1 = (const float*)d_in[3];
    const float* B1 = (const float*)d_in[4];
    const float* W2 = (const float*)d_in[5];
    const float* B2 = (const float*)d_in[6];
    const float* HM = (const float*)d_in[7];
    const float* LQ = (const float*)d_in[8];
    const float* LR = (const float*)d_in[9];
    const float* LP0 = (const float*)d_in[10];
    float* out = (float*)d_out;
    ukf_kernel<<<dim3(B_LEN), dim3(64), 0, stream>>>(X0, U, Y, W1, B1, W2, B2,
                                                     HM, LQ, LR, LP0, out);
}